// Round 1
// baseline (224.308 us; speedup 1.0000x reference)
//
#include <hip/hip_runtime.h>

#define MPB 8      // matrices per 256-thread block (32 lanes per matrix)
#define ITERS 20

__global__ __launch_bounds__(256) void sinkhorn30_kernel(
    const float* __restrict__ scores,
    const float* __restrict__ action,
    float* __restrict__ out)
{
  // staged exp(scores): 8 matrices * 900 floats, packed row stride 30
  __shared__ __align__(16) float smat[MPB * 900];
  // per-matrix u/v exchange buffer (30 used of 32)
  __shared__ __align__(16) float svec[MPB][32];

  const int tid = threadIdx.x;
  const long long blk = blockIdx.x;

  // ---- stage exp(scores) into LDS: coalesced float4 loads ----
  {
    const float4* __restrict__ g =
        (const float4*)(scores + blk * (long long)(MPB * 900));
    float4* s = (float4*)smat;
#pragma unroll
    for (int k = 0; k < 7; ++k) {
      const int idx = tid + k * 256;
      float4 x = g[idx];
      float4 e;
      e.x = __expf(x.x); e.y = __expf(x.y);
      e.z = __expf(x.z); e.w = __expf(x.w);
      s[idx] = e;
    }
    if (tid < 8) {  // 1800 float4s total: 7*256 = 1792 + 8
      const int idx = tid + 1792;
      float4 x = g[idx];
      float4 e;
      e.x = __expf(x.x); e.y = __expf(x.y);
      e.z = __expf(x.z); e.w = __expf(x.w);
      s[idx] = e;
    }
  }
  __syncthreads();

  const int m = tid >> 5;          // matrix within block (0..7)
  const int r = tid & 31;          // row/col owned by this lane
  const bool active = (r < 30);
  const int rr = active ? r : 0;   // clamp for safe LDS reads
  const float* __restrict__ mp = smat + m * 900;

  // row r of K (pairs) — lane-local operand for u-step and final matvec
  float2 row[15];
  {
    const float2* rp = (const float2*)(mp + rr * 30);  // 120B -> 8B aligned
#pragma unroll
    for (int k = 0; k < 15; ++k) row[k] = rp[k];
  }
  // column r of K — lane-local operand for v-step (consecutive banks/lane)
  float col[30];
#pragma unroll
  for (int k = 0; k < 30; ++k) col[k] = mp[k * 30 + rr];

  // v starts at 1 (first u-step is plain row-sum of K)
  float2 v[15];
#pragma unroll
  for (int k = 0; k < 15; ++k) { v[k].x = 1.f; v[k].y = 1.f; }

  const float2* vp = (const float2*)(&svec[m][0]);  // broadcast gather ptr
  float u = 1.f;

  for (int it = 0; it < ITERS; ++it) {
    // ---- u-step: u_r = 1 / dot(K_row_r, v) ----
    float s0 = 0.f, s1 = 0.f, s2 = 0.f, s3 = 0.f;
#pragma unroll
    for (int k = 0; k < 15; k += 2) {
      s0 = fmaf(row[k].x, v[k].x, s0);
      s1 = fmaf(row[k].y, v[k].y, s1);
    }
#pragma unroll
    for (int k = 1; k < 15; k += 2) {
      s2 = fmaf(row[k].x, v[k].x, s2);
      s3 = fmaf(row[k].y, v[k].y, s3);
    }
    u = __builtin_amdgcn_rcpf((s0 + s2) + (s1 + s3));
    if (active) svec[m][r] = u;
    // make the write visible to the other lanes of this wave
    asm volatile("s_waitcnt lgkmcnt(0)" ::: "memory");

    // ---- v-step: v_r = 1 / dot(K_col_r, u) ----
    float t0 = 0.f, t1 = 0.f, t2 = 0.f, t3 = 0.f;
#pragma unroll
    for (int k = 0; k < 15; k += 2) {
      const float2 g2 = vp[k];      // broadcast read of u pair
      t0 = fmaf(col[2 * k],     g2.x, t0);
      t1 = fmaf(col[2 * k + 1], g2.y, t1);
    }
#pragma unroll
    for (int k = 1; k < 15; k += 2) {
      const float2 g2 = vp[k];
      t2 = fmaf(col[2 * k],     g2.x, t2);
      t3 = fmaf(col[2 * k + 1], g2.y, t3);
    }
    const float vnew = __builtin_amdgcn_rcpf((t0 + t2) + (t1 + t3));
    // vnew depends on ALL gathered u values -> write cannot pass the reads
    if (active) svec[m][r] = vnew;
    asm volatile("s_waitcnt lgkmcnt(0)" ::: "memory");
    // gather the full fresh v for the next u-step / final matvec
#pragma unroll
    for (int k = 0; k < 15; ++k) v[k] = vp[k];
  }

  // ---- epilogue: out_i = u_i * sum_j K_ij * v_j * a_j ----
  const long long b = blk * MPB + m;
  // protect the final v-gather reads before overwriting svec with action
  asm volatile("s_waitcnt lgkmcnt(0)" ::: "memory");
  if (active) svec[m][r] = action[b * 30 + r];
  asm volatile("s_waitcnt lgkmcnt(0)" ::: "memory");

  float y0 = 0.f, y1 = 0.f;
#pragma unroll
  for (int k = 0; k < 15; ++k) {
    const float2 a2 = vp[k];
    y0 = fmaf(row[k].x, v[k].x * a2.x, y0);
    y1 = fmaf(row[k].y, v[k].y * a2.y, y1);
  }
  if (active) out[b * 30 + r] = u * (y0 + y1);
}

extern "C" void kernel_launch(void* const* d_in, const int* in_sizes, int n_in,
                              void* d_out, int out_size, void* d_ws, size_t ws_size,
                              hipStream_t stream) {
  const float* scores = (const float*)d_in[0];
  const float* action = (const float*)d_in[1];
  float* out = (float*)d_out;

  const int B = in_sizes[1] / 30;       // 131072 matrices
  const int blocks = B / MPB;           // 16384 blocks of 256 threads
  sinkhorn30_kernel<<<blocks, 256, 0, stream>>>(scores, action, out);
}